// Round 3
// baseline (148.645 us; speedup 1.0000x reference)
//
#include <hip/hip_runtime.h>
#include <stdint.h>

#define BATCH   8
#define NITEMS  1000000
#define NB      4096          // value-based bins: bin = floor(s * 4096)
#define NBLK    128           // blocks per batch for streaming passes
#define CAP     32768         // per-batch candidate capacity
#define IMG_W   768.0f
#define IMG_H   432.0f

static __device__ __forceinline__ float clip0(float v, float hi) {
    return fminf(fmaxf(v, 0.0f), hi);
}

static __device__ __forceinline__ unsigned val_bin(float s) {
    int b = (int)(s * (float)NB);
    if (b > NB - 1) b = NB - 1;
    if (b < 0) b = 0;
    return (unsigned)b;
}

// ---------------- kernel 0: zero counters + meta ----------------
__global__ void k_zero(unsigned* __restrict__ ctr,
                       unsigned* __restrict__ meta) {
    int idx = blockIdx.x * blockDim.x + threadIdx.x;
    int total = BATCH * NB;
    for (int i = idx; i < total; i += gridDim.x * blockDim.x) ctr[i] = 0u;
    if (idx < BATCH * 4) meta[idx] = 0u;
}

// ---------------- kernel 1: masked score bits + value-bin LDS histogram ----------------
__global__ __launch_bounds__(512)
void k_bits_hist(const float* __restrict__ scores,
                 const float4* __restrict__ rps,
                 unsigned* __restrict__ bits_arr,
                 unsigned short* __restrict__ partial) {
    __shared__ unsigned h[NB];
    const int b = blockIdx.y, blk = blockIdx.x, tid = threadIdx.x;
    for (int k = tid; k < NB; k += 512) h[k] = 0u;
    __syncthreads();
    const int base = b * NITEMS;
    for (int i = blk * 512 + tid; i < NITEMS; i += NBLK * 512) {
        float4 box = rps[base + i];
        float s = scores[base + i];
        float x1 = clip0(box.x - box.z * 0.5f, IMG_W);
        float x2 = clip0(box.x + box.z * 0.5f, IMG_W);
        float y1 = clip0(box.y - box.w * 0.5f, IMG_H);
        float y2 = clip0(box.y + box.w * 0.5f, IMG_H);
        float nw = x2 - x1, nh = y2 - y1;
        bool m = (nw > 16.0f) && (nh > 16.0f);
        float sm = m ? s : 0.0f;
        unsigned bits = __float_as_uint(sm);
        bits_arr[base + i] = bits;
        if (bits) atomicAdd(&h[val_bin(sm)], 1u);
    }
    __syncthreads();
    unsigned short* dst = partial + ((size_t)(b * NBLK + blk)) * NB;
    for (int k = tid; k < NB; k += 512) dst[k] = (unsigned short)h[k];
}

// ---------------- reduce: sum per-block partial hists ----------------
__global__ __launch_bounds__(256)
void k_reduce(const unsigned short* __restrict__ partial,
              unsigned* __restrict__ hist) {
    const int b = blockIdx.y;
    const int g = blockIdx.x * 256 + threadIdx.x;    // grid.x = NB/256
    const unsigned short* p = partial + (size_t)b * NBLK * NB + g;
    unsigned s = 0;
    for (int k = 0; k < NBLK; k++) s += p[(size_t)k * NB];
    hist[b * NB + g] = s;
}

// ---------------- suffix scan over NB bins; find boundary bin ----------------
// meta[0]=cbb, meta[1]=nAbove, meta[3]=candTotal
__global__ __launch_bounds__(1024)
void k_scan(const unsigned* __restrict__ hist,
            unsigned* __restrict__ suffix,
            unsigned* __restrict__ meta,
            int K) {
    const int b = blockIdx.x, tid = threadIdx.x;
    __shared__ unsigned lh[NB];
    __shared__ unsigned sc[1024];
    const unsigned* h = hist + b * NB;
    for (int k = tid; k < NB; k += 1024) lh[k] = h[k];
    __syncthreads();
    unsigned c[4], p[4];
    unsigned run = 0;
    for (int k = 0; k < 4; k++) {
        int r = tid * 4 + k;                  // reversed index
        c[k] = lh[NB - 1 - r];
        run += c[k];
        p[k] = run;                           // inclusive within thread
    }
    sc[tid] = run;
    __syncthreads();
    unsigned x = run;
    for (int off = 1; off < 1024; off <<= 1) {
        unsigned t = (tid >= off) ? sc[tid - off] : 0u;
        __syncthreads();
        x += t;
        sc[tid] = x;
        __syncthreads();
    }
    unsigned exclBase = x - run;
    for (int k = 0; k < 4; k++) {
        int r = tid * 4 + k;
        int g = NB - 1 - r;
        unsigned excl = exclBase + p[k] - c[k];    // count strictly above bin g
        suffix[b * NB + g] = excl;
        if (excl < (unsigned)K && excl + c[k] >= (unsigned)K) {
            meta[b * 4 + 0] = (unsigned)g;         // boundary bin
            meta[b * 4 + 1] = excl;                // nAbove
            meta[b * 4 + 3] = excl + c[k];         // candTotal
        }
    }
}

// ---------------- compact candidates into segmented slots ----------------
__global__ __launch_bounds__(512)
void k_compact(const unsigned* __restrict__ bits_arr,
               const unsigned* __restrict__ meta,
               const unsigned* __restrict__ csuf,
               unsigned* __restrict__ ctr,
               unsigned long long* __restrict__ cand) {
    const int b = blockIdx.y;
    const unsigned cbb = meta[b * 4 + 0];
    const int base = b * NITEMS;
    for (int i = blockIdx.x * 512 + threadIdx.x; i < NITEMS; i += NBLK * 512) {
        unsigned bits = bits_arr[base + i];
        if (!bits) continue;
        unsigned g = val_bin(__uint_as_float(bits));
        if (g < cbb) continue;
        unsigned slot = csuf[b * NB + g] + atomicAdd(&ctr[b * NB + g], 1u);
        if (slot < CAP)
            cand[(size_t)b * CAP + slot] =
                ((unsigned long long)bits << 32) | (unsigned)(~(unsigned)i);
    }
}

// ---------------- rank within segment, gather, write outputs ----------------
__global__ __launch_bounds__(256)
void k_rank_out(const unsigned long long* __restrict__ cand,
                const unsigned* __restrict__ meta,
                const unsigned* __restrict__ csuf,
                const unsigned* __restrict__ chist,
                const float4* __restrict__ rps,
                float* __restrict__ out,
                int K) {
    const int b = blockIdx.y;
    unsigned total = meta[b * 4 + 3];
    if (total > CAP) total = CAP;
    const unsigned p = blockIdx.x * 256 + threadIdx.x;
    if (p >= total) return;
    const unsigned long long key = cand[(size_t)b * CAP + p];
    const unsigned bits = (unsigned)(key >> 32);
    const unsigned g = val_bin(__uint_as_float(bits));
    unsigned sbase = csuf[b * NB + g];
    unsigned send = sbase + chist[b * NB + g];
    if (send > total) send = total;
    unsigned rank = sbase;
    for (unsigned j = sbase; j < send; j++)
        rank += (cand[(size_t)b * CAP + j] > key) ? 1u : 0u;
    if (rank < (unsigned)K) {
        unsigned idx = ~((unsigned)key);
        float s = __uint_as_float(bits);
        float4 box = rps[(size_t)b * NITEMS + idx];
        float x1 = clip0(box.x - box.z * 0.5f, IMG_W);
        float x2 = clip0(box.x + box.z * 0.5f, IMG_W);
        float y1 = clip0(box.y - box.w * 0.5f, IMG_H);
        float y2 = clip0(box.y + box.w * 0.5f, IMG_H);
        float nw = x2 - x1, nh = y2 - y1;
        float nx = x1 + nw * 0.5f, ny = y1 + nh * 0.5f;
        ((float4*)out)[(size_t)b * K + rank] = make_float4(nx, ny, nw, nh);
        out[(size_t)BATCH * K * 4 + (size_t)b * K + rank] = s;
    }
}

extern "C" void kernel_launch(void* const* d_in, const int* in_sizes, int n_in,
                              void* d_out, int out_size, void* d_ws, size_t ws_size,
                              hipStream_t stream) {
    const float*  scores = (const float*)d_in[0];
    const float4* rps    = (const float4*)d_in[1];
    const int K = out_size / (BATCH * 5);               // 12000

    uint8_t* w = (uint8_t*)d_ws;
    unsigned* bits_arr        = (unsigned*)(w);                     // 32,000,000 B
    unsigned short* partial   = (unsigned short*)(w + 32000000);    // 8,388,608 B
    unsigned* chist           = (unsigned*)(w + 40500000);          // 131,072 B
    unsigned* csuf            = (unsigned*)(w + 40700000);          // 131,072 B
    unsigned* ctr             = (unsigned*)(w + 40900000);          // 131,072 B
    unsigned* meta            = (unsigned*)(w + 41100000);          // 128 B
    unsigned long long* cand  = (unsigned long long*)(w + 41200000); // 2,097,152 B

    k_zero<<<dim3(256), dim3(256), 0, stream>>>(ctr, meta);
    k_bits_hist<<<dim3(NBLK, BATCH), dim3(512), 0, stream>>>(scores, rps, bits_arr, partial);
    k_reduce<<<dim3(NB / 256, BATCH), dim3(256), 0, stream>>>(partial, chist);
    k_scan<<<dim3(BATCH), dim3(1024), 0, stream>>>(chist, csuf, meta, K);
    k_compact<<<dim3(NBLK, BATCH), dim3(512), 0, stream>>>(bits_arr, meta, csuf, ctr, cand);
    k_rank_out<<<dim3(CAP / 256, BATCH), dim3(256), 0, stream>>>(cand, meta, csuf, chist,
                                                                 rps, (float*)d_out, K);
}

// Round 4
// 84.907 us; speedup vs baseline: 1.7507x; 1.7507x over previous
//
#include <hip/hip_runtime.h>
#include <stdint.h>

#define BATCH   8
#define NITEMS  1000000
#define NC      64            // coarse value bins: floor(s*64)
#define NF      4096          // fine bins within one coarse bin
#define NBLK    128           // blocks per batch for streaming passes
#define CAP     32768         // per-batch candidate capacity
#define TOPBIN  (NC - 1)
#define IMG_W   768.0f
#define IMG_H   432.0f

static __device__ __forceinline__ float clip0(float v, float hi) {
    return fminf(fmaxf(v, 0.0f), hi);
}
static __device__ __forceinline__ int cbin(float s) {
    int g = (int)(s * (float)NC);
    return g > NC - 1 ? NC - 1 : (g < 0 ? 0 : g);
}
static __device__ __forceinline__ int fbin(float s, int g) {
    int f = (int)(s * (float)(NC * NF)) - g * NF;   // pow-2 muls: exact, monotone
    return f > NF - 1 ? NF - 1 : (f < 0 ? 0 : f);
}
static __device__ __forceinline__ unsigned mkbits(float4 box, float s) {
    float x1 = clip0(box.x - box.z * 0.5f, IMG_W);
    float x2 = clip0(box.x + box.z * 0.5f, IMG_W);
    float y1 = clip0(box.y - box.w * 0.5f, IMG_H);
    float y2 = clip0(box.y + box.w * 0.5f, IMG_H);
    bool m = ((x2 - x1) > 16.0f) && ((y2 - y1) > 16.0f);
    return __float_as_uint(m ? s : 0.0f);
}

// ---- kernel 1: bits + coarse hist + speculative fine hist of top bin ----
__global__ __launch_bounds__(512)
void k_bits_hist(const float* __restrict__ scores,
                 const float4* __restrict__ rps,
                 uint4* __restrict__ bits_arr,
                 unsigned short* __restrict__ p1,
                 unsigned short* __restrict__ p2) {
    __shared__ unsigned h1[NC];
    __shared__ unsigned h2[NF];
    const int b = blockIdx.y, blk = blockIdx.x, tid = threadIdx.x;
    if (tid < NC) h1[tid] = 0u;
    for (int k = tid; k < NF; k += 512) h2[k] = 0u;
    __syncthreads();
    const int base = b * NITEMS;
    for (int i0 = (blk * 512 + tid) * 4; i0 < NITEMS; i0 += NBLK * 512 * 4) {
        const float4 sc = *(const float4*)(scores + base + i0);
        const float4 bx0 = rps[base + i0 + 0];
        const float4 bx1 = rps[base + i0 + 1];
        const float4 bx2 = rps[base + i0 + 2];
        const float4 bx3 = rps[base + i0 + 3];
        uint4 ob;
        ob.x = mkbits(bx0, sc.x);
        ob.y = mkbits(bx1, sc.y);
        ob.z = mkbits(bx2, sc.z);
        ob.w = mkbits(bx3, sc.w);
        unsigned arr[4] = {ob.x, ob.y, ob.z, ob.w};
        #pragma unroll
        for (int j = 0; j < 4; j++) {
            unsigned bits = arr[j];
            if (bits) {
                float s = __uint_as_float(bits);
                int g = cbin(s);
                atomicAdd(&h1[g], 1u);
                if (g == TOPBIN) atomicAdd(&h2[fbin(s, TOPBIN)], 1u);
            }
        }
        bits_arr[(base + i0) >> 2] = ob;
    }
    __syncthreads();
    const size_t row1 = (size_t)(b * NBLK + blk) * NC;
    if (tid < NC) p1[row1 + tid] = (unsigned short)h1[tid];
    const size_t row2 = (size_t)(b * NBLK + blk) * NF;
    for (int k = tid; k < NF; k += 512) p2[row2 + k] = (unsigned short)h2[k];
}

// ---- kernel 2: reduce coarse partials + serial suffix scan (64 bins) ----
__global__ __launch_bounds__(256)
void k_scan1(const unsigned short* __restrict__ p1,
             unsigned* __restrict__ chist64,
             unsigned* __restrict__ csuf64,
             unsigned* __restrict__ ctrA,
             unsigned* __restrict__ meta,
             int K) {
    const int b = blockIdx.x, tid = threadIdx.x;
    __shared__ unsigned sm[256];
    const int bin = tid & (NC - 1);
    const int chunk = tid >> 6;                   // 4 chunks x 32 rows
    unsigned s = 0;
    for (int k = chunk * 32; k < chunk * 32 + 32; k++)
        s += p1[(size_t)(b * NBLK + k) * NC + bin];
    sm[tid] = s;
    __syncthreads();
    if (tid < NC)
        sm[tid] = sm[tid] + sm[64 + tid] + sm[128 + tid] + sm[192 + tid];
    __syncthreads();
    if (tid == 0) {
        unsigned run = 0, cbb = 0, nAb = 0;
        bool found = false;
        for (int g = NC - 1; g >= 0; g--) {
            unsigned c = sm[g];
            chist64[b * NC + g] = c;
            csuf64[b * NC + g] = run;
            if (!found && run < (unsigned)K && run + c >= (unsigned)K) {
                cbb = (unsigned)g; nAb = run; found = true;
            }
            run += c;
        }
        meta[b * 4 + 0] = cbb;
        meta[b * 4 + 1] = nAb;
    }
    if (tid < NC) ctrA[b * NC + tid] = 0u;
}

// ---- kernel 3: generic fallback fine hist (early-exits when cbb==TOPBIN) ----
__global__ __launch_bounds__(512)
void k_fine_fb(const unsigned* __restrict__ bits_arr,
               const unsigned* __restrict__ meta,
               unsigned short* __restrict__ p2) {
    const int b = blockIdx.y, blk = blockIdx.x, tid = threadIdx.x;
    const unsigned cbb = meta[b * 4 + 0];
    if (cbb == TOPBIN) return;                    // speculative hist already valid
    __shared__ unsigned h2[NF];
    for (int k = tid; k < NF; k += 512) h2[k] = 0u;
    __syncthreads();
    const int base = b * NITEMS;
    for (int i = blk * 512 + tid; i < NITEMS; i += NBLK * 512) {
        unsigned bits = bits_arr[base + i];
        if (!bits) continue;
        float s = __uint_as_float(bits);
        if ((unsigned)cbin(s) == cbb) atomicAdd(&h2[fbin(s, (int)cbb)], 1u);
    }
    __syncthreads();
    const size_t row = (size_t)(b * NBLK + blk) * NF;
    for (int k = tid; k < NF; k += 512) p2[row + k] = (unsigned short)h2[k];
}

// ---- kernel 4: reduce fine partials + parallel suffix scan (4096 bins) ----
__global__ __launch_bounds__(1024)
void k_scan2(const unsigned short* __restrict__ p2,
             unsigned* __restrict__ fhist,
             unsigned* __restrict__ fsuf,
             unsigned* __restrict__ ctrB,
             unsigned* __restrict__ meta,
             int K) {
    const int b = blockIdx.x, tid = threadIdx.x;
    __shared__ unsigned sc[1024];
    const int binbase = 4 * (1023 - tid);         // reversed ownership
    unsigned a0 = 0, a1 = 0, a2 = 0, a3 = 0;
    for (int k = 0; k < NBLK; k++) {
        const ushort4 v = *(const ushort4*)(p2 + (size_t)(b * NBLK + k) * NF + binbase);
        a0 += v.x; a1 += v.y; a2 += v.z; a3 += v.w;
    }
    unsigned cw[4] = {a3, a2, a1, a0};            // reversed (descending bin)
    unsigned pin[4];
    unsigned run = 0;
    #pragma unroll
    for (int k = 0; k < 4; k++) { run += cw[k]; pin[k] = run; }
    sc[tid] = run;
    __syncthreads();
    unsigned x = run;
    for (int off = 1; off < 1024; off <<= 1) {
        unsigned t = (tid >= off) ? sc[tid - off] : 0u;
        __syncthreads();
        x += t;
        sc[tid] = x;
        __syncthreads();
    }
    const unsigned exclBase = x - run;
    const unsigned nAb = meta[b * 4 + 1];
    #pragma unroll
    for (int k = 0; k < 4; k++) {
        int g = binbase + (3 - k);
        unsigned excl = exclBase + pin[k] - cw[k];
        fsuf[b * NF + g] = excl;
        fhist[b * NF + g] = cw[k];
        unsigned t0 = nAb + excl;
        if (t0 < (unsigned)K && t0 + cw[k] >= (unsigned)K) {
            meta[b * 4 + 2] = (unsigned)g;        // fine boundary bin
            meta[b * 4 + 3] = t0 + cw[k];         // candTotal
        }
    }
    if (tid == 0 && nAb + sc[1023] < (unsigned)K) {
        meta[b * 4 + 2] = 0u;
        meta[b * 4 + 3] = nAb + sc[1023];
    }
    ctrB[b * NF + tid * 4 + 0] = 0u;
    ctrB[b * NF + tid * 4 + 1] = 0u;
    ctrB[b * NF + tid * 4 + 2] = 0u;
    ctrB[b * NF + tid * 4 + 3] = 0u;
}

// ---- kernel 5: compact candidates into (tiny) segmented slots ----
__global__ __launch_bounds__(512)
void k_compact(const uint4* __restrict__ bits_arr,
               const unsigned* __restrict__ meta,
               const unsigned* __restrict__ csuf64,
               const unsigned* __restrict__ fsuf,
               unsigned* __restrict__ ctrA,
               unsigned* __restrict__ ctrB,
               unsigned long long* __restrict__ cand) {
    const int b = blockIdx.y;
    const unsigned cbb = meta[b * 4 + 0];
    const unsigned nAb = meta[b * 4 + 1];
    const unsigned fb  = meta[b * 4 + 2];
    const int base = b * NITEMS;
    for (int i0 = (blockIdx.x * 512 + threadIdx.x) * 4; i0 < NITEMS;
         i0 += NBLK * 512 * 4) {
        uint4 v = bits_arr[(base + i0) >> 2];
        unsigned arr[4] = {v.x, v.y, v.z, v.w};
        #pragma unroll
        for (int j = 0; j < 4; j++) {
            unsigned bits = arr[j];
            if (!bits) continue;
            float s = __uint_as_float(bits);
            int g = cbin(s);
            if ((unsigned)g < cbb) continue;
            unsigned slot;
            if ((unsigned)g > cbb) {
                slot = csuf64[b * NC + g] + atomicAdd(&ctrA[b * NC + g], 1u);
            } else {
                int f = fbin(s, g);
                if ((unsigned)f < fb) continue;
                slot = nAb + fsuf[b * NF + f] + atomicAdd(&ctrB[b * NF + f], 1u);
            }
            if (slot < CAP)
                cand[(size_t)b * CAP + slot] =
                    ((unsigned long long)bits << 32) | (unsigned)(~(unsigned)(i0 + j));
        }
    }
}

// ---- kernel 6: rank within tiny segment, gather, write outputs ----
__global__ __launch_bounds__(256)
void k_rank_out(const unsigned long long* __restrict__ cand,
                const unsigned* __restrict__ meta,
                const unsigned* __restrict__ csuf64,
                const unsigned* __restrict__ chist64,
                const unsigned* __restrict__ fsuf,
                const unsigned* __restrict__ fhist,
                const float4* __restrict__ rps,
                float* __restrict__ out,
                int K) {
    const int b = blockIdx.y;
    unsigned total = meta[b * 4 + 3];
    if (total > CAP) total = CAP;
    const unsigned p = blockIdx.x * 256 + threadIdx.x;
    if (p >= total) return;
    const unsigned long long key = cand[(size_t)b * CAP + p];
    const unsigned bits = (unsigned)(key >> 32);
    const float s = __uint_as_float(bits);
    const unsigned cbb = meta[b * 4 + 0];
    const unsigned nAb = meta[b * 4 + 1];
    int g = cbin(s);
    unsigned sbase, scnt;
    if ((unsigned)g > cbb) {
        sbase = csuf64[b * NC + g];
        scnt  = chist64[b * NC + g];
    } else {
        int f = fbin(s, g);
        sbase = nAb + fsuf[b * NF + f];
        scnt  = fhist[b * NF + f];
    }
    unsigned send = sbase + scnt;
    if (send > total) send = total;
    unsigned rank = sbase;
    for (unsigned j = sbase; j < send; j++)
        rank += (cand[(size_t)b * CAP + j] > key) ? 1u : 0u;
    if (rank < (unsigned)K) {
        unsigned idx = ~((unsigned)key);
        float4 box = rps[(size_t)b * NITEMS + idx];
        float x1 = clip0(box.x - box.z * 0.5f, IMG_W);
        float x2 = clip0(box.x + box.z * 0.5f, IMG_W);
        float y1 = clip0(box.y - box.w * 0.5f, IMG_H);
        float y2 = clip0(box.y + box.w * 0.5f, IMG_H);
        float nw = x2 - x1, nh = y2 - y1;
        float nx = x1 + nw * 0.5f, ny = y1 + nh * 0.5f;
        ((float4*)out)[(size_t)b * K + rank] = make_float4(nx, ny, nw, nh);
        out[(size_t)BATCH * K * 4 + (size_t)b * K + rank] = s;
    }
}

extern "C" void kernel_launch(void* const* d_in, const int* in_sizes, int n_in,
                              void* d_out, int out_size, void* d_ws, size_t ws_size,
                              hipStream_t stream) {
    const float*  scores = (const float*)d_in[0];
    const float4* rps    = (const float4*)d_in[1];
    const int K = out_size / (BATCH * 5);               // 12000

    uint8_t* w = (uint8_t*)d_ws;
    uint4* bits_arr          = (uint4*)(w);                         // 32,000,000 B
    unsigned short* p1       = (unsigned short*)(w + 32000000);     // 131,072 B
    unsigned short* p2       = (unsigned short*)(w + 32200000);     // 8,388,608 B
    unsigned* chist64        = (unsigned*)(w + 40600000);           // 2 KiB
    unsigned* csuf64         = (unsigned*)(w + 40610000);           // 2 KiB
    unsigned* fhist          = (unsigned*)(w + 40700000);           // 128 KiB
    unsigned* fsuf           = (unsigned*)(w + 40900000);           // 128 KiB
    unsigned* ctrA           = (unsigned*)(w + 41100000);           // 2 KiB
    unsigned* ctrB           = (unsigned*)(w + 41200000);           // 128 KiB
    unsigned* meta           = (unsigned*)(w + 41400000);           // 128 B
    unsigned long long* cand = (unsigned long long*)(w + 41500000); // 2 MiB

    k_bits_hist<<<dim3(NBLK, BATCH), dim3(512), 0, stream>>>(scores, rps, bits_arr, p1, p2);
    k_scan1<<<dim3(BATCH), dim3(256), 0, stream>>>(p1, chist64, csuf64, ctrA, meta, K);
    k_fine_fb<<<dim3(NBLK, BATCH), dim3(512), 0, stream>>>((const unsigned*)bits_arr, meta, p2);
    k_scan2<<<dim3(BATCH), dim3(1024), 0, stream>>>(p2, fhist, fsuf, ctrB, meta, K);
    k_compact<<<dim3(NBLK, BATCH), dim3(512), 0, stream>>>(bits_arr, meta, csuf64, fsuf,
                                                           ctrA, ctrB, cand);
    k_rank_out<<<dim3(CAP / 256, BATCH), dim3(256), 0, stream>>>(cand, meta, csuf64, chist64,
                                                                 fsuf, fhist, rps,
                                                                 (float*)d_out, K);
}